// Round 1
// baseline (276.271 us; speedup 1.0000x reference)
//
#include <hip/hip_runtime.h>

#define TPB 256
#define PPT 4   // pixels per thread

__global__ __launch_bounds__(TPB) void uvtrans_kernel(
    const float* __restrict__ depth0,
    const float* __restrict__ R0,
    const float* __restrict__ t0,
    const float* __restrict__ R1,
    const float* __restrict__ t1,
    const float* __restrict__ K,
    const float* __restrict__ ray,
    float* __restrict__ out_uv,
    float* __restrict__ out_d,
    int N)
{
    __shared__ float sR0[9], sR1[9], st0[3], st1[3], sK[9];
    const int b = blockIdx.y;
    const int tid = threadIdx.x;
    if (tid < 9)        sR0[tid]      = R0[b * 9 + tid];
    else if (tid < 18)  sR1[tid - 9]  = R1[b * 9 + tid - 9];
    else if (tid < 21)  st0[tid - 18] = t0[b * 3 + tid - 18];
    else if (tid < 24)  st1[tid - 21] = t1[b * 3 + tid - 21];
    else if (tid < 33)  sK[tid - 24]  = K[tid - 24];
    __syncthreads();

    const int n0 = (blockIdx.x * TPB + tid) * PPT;
    if (n0 >= N) return;

    const size_t base = (size_t)b * N + n0;

    const float4 dep = *reinterpret_cast<const float4*>(depth0 + base);
    // ray layout (N,3); n0 % 4 == 0 -> byte offset n0*12 is 16B-aligned
    const float4 r0v = *reinterpret_cast<const float4*>(ray + (size_t)n0 * 3 + 0);
    const float4 r1v = *reinterpret_cast<const float4*>(ray + (size_t)n0 * 3 + 4);
    const float4 r2v = *reinterpret_cast<const float4*>(ray + (size_t)n0 * 3 + 8);

    const float rays[12] = {r0v.x, r0v.y, r0v.z, r0v.w,
                            r1v.x, r1v.y, r1v.z, r1v.w,
                            r2v.x, r2v.y, r2v.z, r2v.w};
    const float deps[4] = {dep.x, dep.y, dep.z, dep.w};

    float uvo[8];
    float dou[4];

    #pragma unroll
    for (int i = 0; i < PPT; ++i) {
        const float dd = deps[i];
        // xyz = depth*ray - t0
        const float p0 = fmaf(dd, rays[3 * i + 0], -st0[0]);
        const float p1 = fmaf(dd, rays[3 * i + 1], -st0[1]);
        const float p2 = fmaf(dd, rays[3 * i + 2], -st0[2]);
        // y = xyz @ R0  (sum_c xyz_c * R0[c][d])
        const float y0 = fmaf(p2, sR0[6], fmaf(p1, sR0[3], p0 * sR0[0]));
        const float y1 = fmaf(p2, sR0[7], fmaf(p1, sR0[4], p0 * sR0[1]));
        const float y2 = fmaf(p2, sR0[8], fmaf(p1, sR0[5], p0 * sR0[2]));
        // z = y @ R1^T + t1  (sum_c y_c * R1[d][c])
        const float z0 = fmaf(y2, sR1[2], fmaf(y1, sR1[1], y0 * sR1[0])) + st1[0];
        const float z1 = fmaf(y2, sR1[5], fmaf(y1, sR1[4], y0 * sR1[3])) + st1[1];
        const float z2 = fmaf(y2, sR1[8], fmaf(y1, sR1[7], y0 * sR1[6])) + st1[2];
        // uv3 = z @ K^T  (sum_c z_c * K[d][c])
        const float u0 = fmaf(z2, sK[2], fmaf(z1, sK[1], z0 * sK[0]));
        const float u1 = fmaf(z2, sK[5], fmaf(z1, sK[4], z0 * sK[3]));
        const float u2 = fmaf(z2, sK[8], fmaf(z1, sK[7], z0 * sK[6]));

        const float denom = fmaxf(u2, 0.0f) + 1e-12f;
        uvo[2 * i + 0] = u0 / denom;
        uvo[2 * i + 1] = u1 / denom;
        dou[i] = u2;
    }

    float4* uvp = reinterpret_cast<float4*>(out_uv + base * 2);
    uvp[0] = make_float4(uvo[0], uvo[1], uvo[2], uvo[3]);
    uvp[1] = make_float4(uvo[4], uvo[5], uvo[6], uvo[7]);
    *reinterpret_cast<float4*>(out_d + base) = make_float4(dou[0], dou[1], dou[2], dou[3]);
}

extern "C" void kernel_launch(void* const* d_in, const int* in_sizes, int n_in,
                              void* d_out, int out_size, void* d_ws, size_t ws_size,
                              hipStream_t stream) {
    const float* depth0 = (const float*)d_in[0];
    const float* R0     = (const float*)d_in[1];
    const float* t0     = (const float*)d_in[2];
    const float* R1     = (const float*)d_in[3];
    const float* t1     = (const float*)d_in[4];
    const float* K      = (const float*)d_in[5];
    const float* ray    = (const float*)d_in[6];

    const int N  = in_sizes[6] / 3;      // ray is (1, H*W, 3)
    const int BS = in_sizes[0] / N;      // depth0 is (BS, H, W)

    float* out    = (float*)d_out;
    float* out_uv = out;                             // (BS, N, 2) flat
    float* out_d  = out + (size_t)BS * N * 2;        // (BS, N, 1) flat

    dim3 grid((N + TPB * PPT - 1) / (TPB * PPT), BS);
    uvtrans_kernel<<<grid, TPB, 0, stream>>>(depth0, R0, t0, R1, t1, K, ray,
                                             out_uv, out_d, N);
}

// Round 3
// 268.116 us; speedup vs baseline: 1.0304x; 1.0304x over previous
//
#include <hip/hip_runtime.h>

#define TPB 256
#define PPT 4   // pixels per thread

typedef float f32x4 __attribute__((ext_vector_type(4)));

__global__ __launch_bounds__(TPB) void uvtrans_kernel(
    const float* __restrict__ depth0,
    const float* __restrict__ R0,
    const float* __restrict__ t0,
    const float* __restrict__ R1,
    const float* __restrict__ t1,
    const float* __restrict__ K,
    const float* __restrict__ ray,
    float* __restrict__ out_uv,
    float* __restrict__ out_d,
    int N)
{
    const int b = blockIdx.y;

    // All wave-uniform (indexed by blockIdx.y) -> compiler lowers to s_load
    // into SGPRs; no LDS, no __syncthreads.
    const float a00 = R0[b * 9 + 0], a01 = R0[b * 9 + 1], a02 = R0[b * 9 + 2];
    const float a10 = R0[b * 9 + 3], a11 = R0[b * 9 + 4], a12 = R0[b * 9 + 5];
    const float a20 = R0[b * 9 + 6], a21 = R0[b * 9 + 7], a22 = R0[b * 9 + 8];
    const float b00 = R1[b * 9 + 0], b01 = R1[b * 9 + 1], b02 = R1[b * 9 + 2];
    const float b10 = R1[b * 9 + 3], b11 = R1[b * 9 + 4], b12 = R1[b * 9 + 5];
    const float b20 = R1[b * 9 + 6], b21 = R1[b * 9 + 7], b22 = R1[b * 9 + 8];
    const float t00 = t0[b * 3 + 0], t01 = t0[b * 3 + 1], t02 = t0[b * 3 + 2];
    const float t10 = t1[b * 3 + 0], t11 = t1[b * 3 + 1], t12 = t1[b * 3 + 2];
    const float k00 = K[0], k01 = K[1], k02 = K[2];
    const float k10 = K[3], k11 = K[4], k12 = K[5];
    const float k20 = K[6], k21 = K[7], k22 = K[8];

    const int n0 = (blockIdx.x * TPB + threadIdx.x) * PPT;
    if (n0 >= N) return;

    const size_t base = (size_t)b * N + n0;

    // depth streamed once -> nontemporal; ray reused across 64 batches -> keep cached
    const f32x4 dep = __builtin_nontemporal_load(
        reinterpret_cast<const f32x4*>(depth0 + base));
    const f32x4 r0v = *reinterpret_cast<const f32x4*>(ray + (size_t)n0 * 3 + 0);
    const f32x4 r1v = *reinterpret_cast<const f32x4*>(ray + (size_t)n0 * 3 + 4);
    const f32x4 r2v = *reinterpret_cast<const f32x4*>(ray + (size_t)n0 * 3 + 8);

    const float rays[12] = {r0v.x, r0v.y, r0v.z, r0v.w,
                            r1v.x, r1v.y, r1v.z, r1v.w,
                            r2v.x, r2v.y, r2v.z, r2v.w};
    const float deps[4] = {dep.x, dep.y, dep.z, dep.w};

    float uvo[8];
    float dou[4];

    #pragma unroll
    for (int i = 0; i < PPT; ++i) {
        const float dd = deps[i];
        // xyz = depth*ray - t0          (same op order as reference)
        const float p0 = fmaf(dd, rays[3 * i + 0], -t00);
        const float p1 = fmaf(dd, rays[3 * i + 1], -t01);
        const float p2 = fmaf(dd, rays[3 * i + 2], -t02);
        // y = xyz @ R0
        const float y0 = fmaf(p2, a20, fmaf(p1, a10, p0 * a00));
        const float y1 = fmaf(p2, a21, fmaf(p1, a11, p0 * a01));
        const float y2 = fmaf(p2, a22, fmaf(p1, a12, p0 * a02));
        // z = y @ R1^T + t1
        const float z0 = fmaf(y2, b02, fmaf(y1, b01, y0 * b00)) + t10;
        const float z1 = fmaf(y2, b12, fmaf(y1, b11, y0 * b10)) + t11;
        const float z2 = fmaf(y2, b22, fmaf(y1, b21, y0 * b20)) + t12;
        // uv3 = z @ K^T
        const float u0 = fmaf(z2, k02, fmaf(z1, k01, z0 * k00));
        const float u1 = fmaf(z2, k12, fmaf(z1, k11, z0 * k10));
        const float u2 = fmaf(z2, k22, fmaf(z1, k21, z0 * k20));

        const float denom = fmaxf(u2, 0.0f) + 1e-12f;
        // fast rcp + one Newton step instead of the full v_div sequence
        float r = __builtin_amdgcn_rcpf(denom);
        r = r * fmaf(-denom, r, 2.0f);
        uvo[2 * i + 0] = u0 * r;
        uvo[2 * i + 1] = u1 * r;
        dou[i] = u2;
    }

    // outputs never re-read -> nontemporal stores (keep L2 for `ray`)
    f32x4* uvp = reinterpret_cast<f32x4*>(out_uv + base * 2);
    f32x4 uv0; uv0.x = uvo[0]; uv0.y = uvo[1]; uv0.z = uvo[2]; uv0.w = uvo[3];
    f32x4 uv1; uv1.x = uvo[4]; uv1.y = uvo[5]; uv1.z = uvo[6]; uv1.w = uvo[7];
    f32x4 dv;  dv.x  = dou[0]; dv.y  = dou[1]; dv.z  = dou[2]; dv.w  = dou[3];
    __builtin_nontemporal_store(uv0, uvp + 0);
    __builtin_nontemporal_store(uv1, uvp + 1);
    __builtin_nontemporal_store(dv, reinterpret_cast<f32x4*>(out_d + base));
}

extern "C" void kernel_launch(void* const* d_in, const int* in_sizes, int n_in,
                              void* d_out, int out_size, void* d_ws, size_t ws_size,
                              hipStream_t stream) {
    const float* depth0 = (const float*)d_in[0];
    const float* R0     = (const float*)d_in[1];
    const float* t0     = (const float*)d_in[2];
    const float* R1     = (const float*)d_in[3];
    const float* t1     = (const float*)d_in[4];
    const float* K      = (const float*)d_in[5];
    const float* ray    = (const float*)d_in[6];

    const int N  = in_sizes[6] / 3;      // ray is (1, H*W, 3)
    const int BS = in_sizes[0] / N;      // depth0 is (BS, H, W)

    float* out    = (float*)d_out;
    float* out_uv = out;                             // (BS, N, 2) flat
    float* out_d  = out + (size_t)BS * N * 2;        // (BS, N, 1) flat

    dim3 grid((N + TPB * PPT - 1) / (TPB * PPT), BS);
    uvtrans_kernel<<<grid, TPB, 0, stream>>>(depth0, R0, t0, R1, t1, K, ray,
                                             out_uv, out_d, N);
}